// Round 6
// baseline (102.252 us; speedup 1.0000x reference)
//
#include <hip/hip_runtime.h>

#define B_SZ  128
#define CH    64
#define T_LEN 4096
#define HID   32
#define INS   3

// ---------------------------------------------------------------------------
// Kernel 1: hypernetwork MLPs. One block per batch sample.
// Writes weight TRANSPOSED as wT[b][i][o] (contiguous in o -> wide s_loads).
// ---------------------------------------------------------------------------
__global__ __launch_bounds__(256) void hyper_mlp_kernel(
    const float* __restrict__ z,
    const float* __restrict__ w_w1, const float* __restrict__ w_b1,
    const float* __restrict__ w_g,  const float* __restrict__ w_beta,
    const float* __restrict__ w_w2, const float* __restrict__ w_b2,
    const float* __restrict__ b_w1, const float* __restrict__ b_b1,
    const float* __restrict__ b_g,  const float* __restrict__ b_beta,
    const float* __restrict__ b_w2, const float* __restrict__ b_b2,
    float* __restrict__ wT,    // [B][CH_in][CH_out]
    float* __restrict__ bias)  // [B][CH]
{
  const int b   = blockIdx.x;
  const int tid = threadIdx.x;

  __shared__ float zs[INS];
  __shared__ float hraw[2][HID];
  __shared__ float hn[2][HID];

  if (tid < INS) zs[tid] = z[b * INS + tid];
  __syncthreads();

  if (tid < 2 * HID) {
    const int grp = tid >> 5;          // 0 = weight-MLP, 1 = bias-MLP
    const int j   = tid & 31;
    const float* w1 = grp ? b_w1 : w_w1;
    const float* b1 = grp ? b_b1 : w_b1;
    hraw[grp][j] = w1[j*3+0]*zs[0] + w1[j*3+1]*zs[1] + w1[j*3+2]*zs[2] + b1[j];
  }
  __syncthreads();

  if (tid < 2 * HID) {
    const int grp = tid >> 5;
    const int j   = tid & 31;
    float mu = 0.f;
    #pragma unroll
    for (int k = 0; k < HID; ++k) mu += hraw[grp][k];
    mu *= (1.0f / HID);
    float var = 0.f;
    #pragma unroll
    for (int k = 0; k < HID; ++k) { float d = hraw[grp][k] - mu; var += d * d; }
    var *= (1.0f / HID);
    const float r  = rsqrtf(var + 1e-5f);
    const float* g  = grp ? b_g    : w_g;
    const float* be = grp ? b_beta : w_beta;
    const float v = (hraw[grp][j] - mu) * r * g[j] + be[j];
    hn[grp][j] = fmaxf(v, 0.f);
  }
  __syncthreads();

  for (int m = tid; m < CH * CH; m += 256) {
    const float* row = w_w2 + m * HID;
    float acc = w_b2[m];
    #pragma unroll
    for (int i = 0; i < HID; ++i) acc += hn[0][i] * row[i];
    // m = o*64 + i  ->  wT[b][i][o]
    wT[(size_t)b * CH * CH + (m & 63) * CH + (m >> 6)] = acc;
  }

  if (tid < CH) {
    const float* row = b_w2 + tid * HID;
    float acc = b_b2[tid];
    #pragma unroll
    for (int i = 0; i < HID; ++i) acc += hn[1][i] * row[i];
    bias[b * CH + tid] = acc;
  }
}

// ---------------------------------------------------------------------------
// Kernel 2: per-batch 64x64 matrix applied to x[b][64][T].
// NO LDS, NO barriers. Block = 256 threads = 4 waves = 2 o-halves x 2
// t-halves; block covers 64 o x 128 t of one b. Wave owns 32 outputs x 64
// unique t (lane = one t). Per i-step per wave: 1 scalar x load (256 B
// coalesced, only 2x shared within block -> L1 trivial), 8 uniform s_loads
// (32 w floats, SGPR; lgkmcnt separate from vmcnt), 32 v_fmac (64 cyc of
// dense FMA). acc[32] fully static -> 32 VGPR, ~48 total -> 8 waves/SIMD.
// Aggregate per CU: ~16 B/cyc L1, ~8 B/cyc unique HBM -> HBM-bound (~43 us
// floor), VALU ~60%+ overlapped, loads stream with no phase barriers.
// ---------------------------------------------------------------------------
__global__ __launch_bounds__(256, 8) void conv1x1_kernel(
    const float* __restrict__ x,
    const float* __restrict__ wT,
    const float* __restrict__ bias,
    float* __restrict__ out)
{
  const int b    = blockIdx.y;
  const int tbi  = blockIdx.x;          // 128-t chunk index
  const int tid  = threadIdx.x;
  const int lane = tid & 63;
  const int wid  = __builtin_amdgcn_readfirstlane(tid >> 6);  // 0..3
  const int oh   = wid & 1;             // o-half: outputs 32*oh .. 32*oh+31
  const int th   = wid >> 1;            // t-half within block

  const int t = tbi * 128 + th * 64 + lane;
  const float* xp = x  + (size_t)b * CH * T_LEN + t;         // + i*T_LEN
  const float* wp = wT + (size_t)b * CH * CH + oh * 32;      // + i*CH, uniform

  float acc[32];
  #pragma unroll
  for (int o = 0; o < 32; ++o) acc[o] = 0.f;

  #pragma unroll 2
  for (int i = 0; i < CH; ++i) {
    const float xv = xp[(size_t)i * T_LEN];                  // per-lane, 256 B/wave
    const float* wrow = wp + i * CH;                         // wave-uniform -> s_load
    #pragma unroll
    for (int o = 0; o < 32; ++o) acc[o] += wrow[o] * xv;
  }

  const float* bp = bias + b * CH + oh * 32;                 // uniform -> SGPR
  float* op = out + ((size_t)b * CH + oh * 32) * T_LEN + t;

  #pragma unroll
  for (int o = 0; o < 32; ++o) {
    op[(size_t)o * T_LEN] = acc[o] + bp[o];
  }
}

extern "C" void kernel_launch(void* const* d_in, const int* in_sizes, int n_in,
                              void* d_out, int out_size, void* d_ws, size_t ws_size,
                              hipStream_t stream) {
  const float* x      = (const float*)d_in[0];
  const float* z      = (const float*)d_in[1];
  const float* w_w1   = (const float*)d_in[2];
  const float* w_b1   = (const float*)d_in[3];
  const float* w_g    = (const float*)d_in[4];
  const float* w_beta = (const float*)d_in[5];
  const float* w_w2   = (const float*)d_in[6];
  const float* w_b2   = (const float*)d_in[7];
  const float* b_w1   = (const float*)d_in[8];
  const float* b_b1   = (const float*)d_in[9];
  const float* b_g    = (const float*)d_in[10];
  const float* b_beta = (const float*)d_in[11];
  const float* b_w2   = (const float*)d_in[12];
  const float* b_b2   = (const float*)d_in[13];

  float* out  = (float*)d_out;
  float* wT   = (float*)d_ws;                      // 128*64*64 floats = 2 MB
  float* bias = wT + (size_t)B_SZ * CH * CH;       // 128*64 floats

  hyper_mlp_kernel<<<B_SZ, 256, 0, stream>>>(
      z, w_w1, w_b1, w_g, w_beta, w_w2, w_b2,
      b_w1, b_b1, b_g, b_beta, b_w2, b_b2, wT, bias);

  dim3 grid(T_LEN / 128, B_SZ);
  conv1x1_kernel<<<grid, 256, 0, stream>>>(x, wT, bias, out);
}

// Round 7
// 88.250 us; speedup vs baseline: 1.1587x; 1.1587x over previous
//
#include <hip/hip_runtime.h>
#include <hip/hip_bf16.h>

#define B_SZ  128
#define CH    64
#define T_LEN 4096
#define HID   32
#define INS   3

typedef __attribute__((ext_vector_type(8))) short short8;   // 8 bf16 (4 VGPRs)
typedef __attribute__((ext_vector_type(4))) float f32x4;

__device__ inline unsigned short f2bf_bits(float f) {
  __hip_bfloat16 h = __float2bfloat16(f);
  union { __hip_bfloat16 h; unsigned short u; } cv;
  cv.h = h;
  return cv.u;
}

// ---------------------------------------------------------------------------
// Kernel 1: hypernetwork MLPs. One block per batch sample.
// Emits weight as bf16 in natural [b][o][i] order (i contiguous -> A-frag is
// one 16B load of 8 consecutive k) + fp32 bias.
// ---------------------------------------------------------------------------
__global__ __launch_bounds__(256) void hyper_mlp_kernel(
    const float* __restrict__ z,
    const float* __restrict__ w_w1, const float* __restrict__ w_b1,
    const float* __restrict__ w_g,  const float* __restrict__ w_beta,
    const float* __restrict__ w_w2, const float* __restrict__ w_b2,
    const float* __restrict__ b_w1, const float* __restrict__ b_b1,
    const float* __restrict__ b_g,  const float* __restrict__ b_beta,
    const float* __restrict__ b_w2, const float* __restrict__ b_b2,
    unsigned short* __restrict__ wbf,  // [B][CH_out][CH_in] bf16 bits
    float* __restrict__ bias)          // [B][CH]
{
  const int b   = blockIdx.x;
  const int tid = threadIdx.x;

  __shared__ float zs[INS];
  __shared__ float hraw[2][HID];
  __shared__ float hn[2][HID];

  if (tid < INS) zs[tid] = z[b * INS + tid];
  __syncthreads();

  if (tid < 2 * HID) {
    const int grp = tid >> 5;          // 0 = weight-MLP, 1 = bias-MLP
    const int j   = tid & 31;
    const float* w1 = grp ? b_w1 : w_w1;
    const float* b1 = grp ? b_b1 : w_b1;
    hraw[grp][j] = w1[j*3+0]*zs[0] + w1[j*3+1]*zs[1] + w1[j*3+2]*zs[2] + b1[j];
  }
  __syncthreads();

  if (tid < 2 * HID) {
    const int grp = tid >> 5;
    const int j   = tid & 31;
    float mu = 0.f;
    #pragma unroll
    for (int k = 0; k < HID; ++k) mu += hraw[grp][k];
    mu *= (1.0f / HID);
    float var = 0.f;
    #pragma unroll
    for (int k = 0; k < HID; ++k) { float d = hraw[grp][k] - mu; var += d * d; }
    var *= (1.0f / HID);
    const float r  = rsqrtf(var + 1e-5f);
    const float* g  = grp ? b_g    : w_g;
    const float* be = grp ? b_beta : w_beta;
    const float v = (hraw[grp][j] - mu) * r * g[j] + be[j];
    hn[grp][j] = fmaxf(v, 0.f);
  }
  __syncthreads();

  // weight head: m = o*64 + i -> natural [o][i] order, bf16
  for (int m = tid; m < CH * CH; m += 256) {
    const float* row = w_w2 + m * HID;
    float acc = w_b2[m];
    #pragma unroll
    for (int i = 0; i < HID; ++i) acc += hn[0][i] * row[i];
    wbf[(size_t)b * CH * CH + m] = f2bf_bits(acc);
  }

  if (tid < CH) {
    const float* row = b_w2 + tid * HID;
    float acc = b_b2[tid];
    #pragma unroll
    for (int i = 0; i < HID; ++i) acc += hn[1][i] * row[i];
    bias[b * CH + tid] = acc;
  }
}

// ---------------------------------------------------------------------------
// Kernel 2: out[b] = W[b] (64x64) @ x[b] (64x4096) + bias, via bf16 MFMA.
// NO LDS, NO barriers. Block = 256 thr = 4 waves; wave owns all 64 o x its
// own 64 t (x elements read exactly once; no inter-wave x sharing). Wave
// preloads 8 A-frags (W rows, 16B contiguous bf16). Per 16-t tile: 2 B-frags
// (per-lane 8 strided x dwords -> cvt to bf16; each 64B x line consumed by
// exactly one load inst) + 8 mfma_f32_16x16x32_bf16 into bias-initialized
// f32x4 accs (C/D: col=lane&15, row=(lane>>4)*4+reg). VALU ~20x lighter than
// scalar-FMA versions -> purely HBM-streaming.
// ---------------------------------------------------------------------------
__global__ __launch_bounds__(256) void conv1x1_mfma(
    const float* __restrict__ x,
    const unsigned short* __restrict__ wbf,
    const float* __restrict__ bias,
    float* __restrict__ out)
{
  const int b    = blockIdx.y;
  const int tid  = threadIdx.x;
  const int lane = tid & 63;
  const int wid  = tid >> 6;        // 0..3
  const int g    = lane >> 4;       // k-group / row-group
  const int r    = lane & 15;

  const int tbase = blockIdx.x * 256 + wid * 64;

  // A-frags: wbf[b][ot*16 + r][ks*32 + g*8 + 0..7] (16B contiguous)
  const unsigned short* wb = wbf + (size_t)b * CH * CH;
  short8 afrag[4][2];
  #pragma unroll
  for (int ot = 0; ot < 4; ++ot)
    #pragma unroll
    for (int ks = 0; ks < 2; ++ks)
      afrag[ot][ks] = *(const short8*)(wb + (ot * 16 + r) * CH + ks * 32 + g * 8);

  // bias: lane's output rows are o = ot*16 + g*4 + q
  float bv[4][4];
  #pragma unroll
  for (int ot = 0; ot < 4; ++ot)
    #pragma unroll
    for (int q = 0; q < 4; ++q)
      bv[ot][q] = bias[b * CH + ot * 16 + g * 4 + q];

  const float* xl = x   + (size_t)b * CH * T_LEN + (size_t)(g * 8) * T_LEN + tbase + r;
  float*       ol = out + (size_t)b * CH * T_LEN + tbase + r;

  #pragma unroll
  for (int nt = 0; nt < 4; ++nt) {
    f32x4 acc0 = {bv[0][0], bv[0][1], bv[0][2], bv[0][3]};
    f32x4 acc1 = {bv[1][0], bv[1][1], bv[1][2], bv[1][3]};
    f32x4 acc2 = {bv[2][0], bv[2][1], bv[2][2], bv[2][3]};
    f32x4 acc3 = {bv[3][0], bv[3][1], bv[3][2], bv[3][3]};

    #pragma unroll
    for (int ks = 0; ks < 2; ++ks) {
      const float* xp = xl + (size_t)(ks * 32) * T_LEN + nt * 16;
      float f0 = xp[0 * (size_t)T_LEN];
      float f1 = xp[1 * (size_t)T_LEN];
      float f2 = xp[2 * (size_t)T_LEN];
      float f3 = xp[3 * (size_t)T_LEN];
      float f4 = xp[4 * (size_t)T_LEN];
      float f5 = xp[5 * (size_t)T_LEN];
      float f6 = xp[6 * (size_t)T_LEN];
      float f7 = xp[7 * (size_t)T_LEN];

      union { short8 s; unsigned short u[8]; } bf;
      bf.u[0] = f2bf_bits(f0); bf.u[1] = f2bf_bits(f1);
      bf.u[2] = f2bf_bits(f2); bf.u[3] = f2bf_bits(f3);
      bf.u[4] = f2bf_bits(f4); bf.u[5] = f2bf_bits(f5);
      bf.u[6] = f2bf_bits(f6); bf.u[7] = f2bf_bits(f7);

      acc0 = __builtin_amdgcn_mfma_f32_16x16x32_bf16(afrag[0][ks], bf.s, acc0, 0, 0, 0);
      acc1 = __builtin_amdgcn_mfma_f32_16x16x32_bf16(afrag[1][ks], bf.s, acc1, 0, 0, 0);
      acc2 = __builtin_amdgcn_mfma_f32_16x16x32_bf16(afrag[2][ks], bf.s, acc2, 0, 0, 0);
      acc3 = __builtin_amdgcn_mfma_f32_16x16x32_bf16(afrag[3][ks], bf.s, acc3, 0, 0, 0);
    }

    // store: out[o = ot*16 + g*4 + q][tbase + nt*16 + r]
    float* os = ol + nt * 16;
    #pragma unroll
    for (int q = 0; q < 4; ++q) {
      os[(size_t)(0 * 16 + g * 4 + q) * T_LEN] = acc0[q];
      os[(size_t)(1 * 16 + g * 4 + q) * T_LEN] = acc1[q];
      os[(size_t)(2 * 16 + g * 4 + q) * T_LEN] = acc2[q];
      os[(size_t)(3 * 16 + g * 4 + q) * T_LEN] = acc3[q];
    }
  }
}

extern "C" void kernel_launch(void* const* d_in, const int* in_sizes, int n_in,
                              void* d_out, int out_size, void* d_ws, size_t ws_size,
                              hipStream_t stream) {
  const float* x      = (const float*)d_in[0];
  const float* z      = (const float*)d_in[1];
  const float* w_w1   = (const float*)d_in[2];
  const float* w_b1   = (const float*)d_in[3];
  const float* w_g    = (const float*)d_in[4];
  const float* w_beta = (const float*)d_in[5];
  const float* w_w2   = (const float*)d_in[6];
  const float* w_b2   = (const float*)d_in[7];
  const float* b_w1   = (const float*)d_in[8];
  const float* b_b1   = (const float*)d_in[9];
  const float* b_g    = (const float*)d_in[10];
  const float* b_beta = (const float*)d_in[11];
  const float* b_w2   = (const float*)d_in[12];
  const float* b_b2   = (const float*)d_in[13];

  float* out = (float*)d_out;
  unsigned short* wbf = (unsigned short*)d_ws;                 // 128*4096 bf16 = 1 MB
  float* bias = (float*)((char*)d_ws + (size_t)B_SZ * CH * CH * sizeof(unsigned short));

  hyper_mlp_kernel<<<B_SZ, 256, 0, stream>>>(
      z, w_w1, w_b1, w_g, w_beta, w_w2, w_b2,
      b_w1, b_b1, b_g, b_beta, b_w2, b_b2, wbf, bias);

  dim3 grid(T_LEN / 256, B_SZ);
  conv1x1_mfma<<<grid, 256, 0, stream>>>(x, wbf, bias, out);
}